// Round 2
// baseline (5905.632 us; speedup 1.0000x reference)
//
#include <hip/hip_runtime.h>
#include <math.h>

#define B_   2
#define S_   1024
#define H_   2048
#define NH_  32
#define NKV_ 8
#define D_   64
#define I_   8192
#define LCK_ 3
#define M_   (B_ * S_)   // 2048 token rows

// ---------------------------------------------------------------------------
// Kernel 1: fused RMSNorm(emb)+RMSNorm(hidden) -> x = concat([e, h], -1)
// one block per token row; H=2048, 256 threads * 8 floats
// ---------------------------------------------------------------------------
__global__ __launch_bounds__(256) void norm_concat_kernel(
    const float* __restrict__ emb, const float* __restrict__ hid,
    const float* __restrict__ w_e, const float* __restrict__ w_h,
    float* __restrict__ x)
{
  const int row = blockIdx.x;
  const int t = threadIdx.x;
  const float* e = emb + (size_t)row * H_;
  const float* h = hid + (size_t)row * H_;

  const float4 ev0 = *(const float4*)&e[t * 4];
  const float4 ev1 = *(const float4*)&e[t * 4 + 1024];
  const float4 hv0 = *(const float4*)&h[t * 4];
  const float4 hv1 = *(const float4*)&h[t * 4 + 1024];

  float se = ev0.x*ev0.x + ev0.y*ev0.y + ev0.z*ev0.z + ev0.w*ev0.w
           + ev1.x*ev1.x + ev1.y*ev1.y + ev1.z*ev1.z + ev1.w*ev1.w;
  float sh = hv0.x*hv0.x + hv0.y*hv0.y + hv0.z*hv0.z + hv0.w*hv0.w
           + hv1.x*hv1.x + hv1.y*hv1.y + hv1.z*hv1.z + hv1.w*hv1.w;

  #pragma unroll
  for (int m = 1; m < 64; m <<= 1) {
    se += __shfl_xor(se, m);
    sh += __shfl_xor(sh, m);
  }
  __shared__ float red[8];
  const int wv = t >> 6;
  if ((t & 63) == 0) { red[wv] = se; red[4 + wv] = sh; }
  __syncthreads();
  se = red[0] + red[1] + red[2] + red[3];
  sh = red[4] + red[5] + red[6] + red[7];

  const float re = 1.0f / sqrtf(se * (1.0f / H_) + 1e-6f);
  const float rh = 1.0f / sqrtf(sh * (1.0f / H_) + 1e-6f);

  const float4 we0 = *(const float4*)&w_e[t * 4];
  const float4 we1 = *(const float4*)&w_e[t * 4 + 1024];
  const float4 wh0 = *(const float4*)&w_h[t * 4];
  const float4 wh1 = *(const float4*)&w_h[t * 4 + 1024];

  float* xr = x + (size_t)row * (2 * H_);
  float4 o;
  o.x = ev0.x * re * we0.x; o.y = ev0.y * re * we0.y; o.z = ev0.z * re * we0.z; o.w = ev0.w * re * we0.w;
  *(float4*)&xr[t * 4] = o;
  o.x = ev1.x * re * we1.x; o.y = ev1.y * re * we1.y; o.z = ev1.z * re * we1.z; o.w = ev1.w * re * we1.w;
  *(float4*)&xr[t * 4 + 1024] = o;
  o.x = hv0.x * rh * wh0.x; o.y = hv0.y * rh * wh0.y; o.z = hv0.z * rh * wh0.z; o.w = hv0.w * rh * wh0.w;
  *(float4*)&xr[2048 + t * 4] = o;
  o.x = hv1.x * rh * wh1.x; o.y = hv1.y * rh * wh1.y; o.z = hv1.z * rh * wh1.z; o.w = hv1.w * rh * wh1.w;
  *(float4*)&xr[2048 + t * 4 + 1024] = o;
}

// ---------------------------------------------------------------------------
// Kernel 2: single-input RMSNorm (for post-attention norm)
// ---------------------------------------------------------------------------
__global__ __launch_bounds__(256) void rmsnorm_kernel(
    const float* __restrict__ in, const float* __restrict__ w, float* __restrict__ outp)
{
  const int row = blockIdx.x;
  const int t = threadIdx.x;
  const float* p = in + (size_t)row * H_;
  const float4 v0 = *(const float4*)&p[t * 4];
  const float4 v1 = *(const float4*)&p[t * 4 + 1024];
  float s = v0.x*v0.x + v0.y*v0.y + v0.z*v0.z + v0.w*v0.w
          + v1.x*v1.x + v1.y*v1.y + v1.z*v1.z + v1.w*v1.w;
  #pragma unroll
  for (int m = 1; m < 64; m <<= 1) s += __shfl_xor(s, m);
  __shared__ float red[4];
  const int wv = t >> 6;
  if ((t & 63) == 0) red[wv] = s;
  __syncthreads();
  s = red[0] + red[1] + red[2] + red[3];
  const float rs = 1.0f / sqrtf(s * (1.0f / H_) + 1e-6f);

  const float4 w0 = *(const float4*)&w[t * 4];
  const float4 w1 = *(const float4*)&w[t * 4 + 1024];
  float* orow = outp + (size_t)row * H_;
  float4 o;
  o.x = v0.x * rs * w0.x; o.y = v0.y * rs * w0.y; o.z = v0.z * rs * w0.z; o.w = v0.w * rs * w0.w;
  *(float4*)&orow[t * 4] = o;
  o.x = v1.x * rs * w1.x; o.y = v1.y * rs * w1.y; o.z = v1.z * rs * w1.z; o.w = v1.w * rs * w1.w;
  *(float4*)&orow[t * 4 + 1024] = o;
}

// ---------------------------------------------------------------------------
// Kernel 3: generic NT GEMM  C[M,N] = A[M,K] * Bw[N,K]^T  (+ epilogue)
// MODE 0: C = acc
// MODE 1: C = acc + X           (residual add)
// MODE 2: C = silu(X) * acc     (SwiGLU: X=gate buffer, acc=up projection)
// NOTE: C and X may ALIAS (MODE 1 final, MODE 2) -> no __restrict__ on them.
// 128x128 tile, BK=16, 256 threads, 8x8 micro-tile.
// LDS staged transposed ([k][m]) so inner loop does ds_read_b128.
// ---------------------------------------------------------------------------
template <int MODE>
__global__ __launch_bounds__(256) void gemm_nt_kernel(
    const float* __restrict__ A, const float* __restrict__ Bw,
    float* C, const float* X,
    int M, int N, int K)
{
  __shared__ __align__(16) float As[16][132];
  __shared__ __align__(16) float Bs[16][132];
  const int t = threadIdx.x;
  const int tr = t >> 4, tc = t & 15;
  const size_t arow0 = (size_t)blockIdx.y * 128;
  const size_t brow0 = (size_t)blockIdx.x * 128;

  float acc[8][8];
  #pragma unroll
  for (int i = 0; i < 8; ++i)
    #pragma unroll
    for (int j = 0; j < 8; ++j) acc[i][j] = 0.f;

  // each thread stages 2 float4 of A and 2 of B per K-tile
  const int f0 = t * 2;
  const int ra  = f0 >> 2;
  const int ka  = (f0 & 3) << 2;
  const int kb2 = ((f0 + 1) & 3) << 2;   // same row, next chunk

  for (int k0 = 0; k0 < K; k0 += 16) {
    const float4 av0 = *(const float4*)&A [(arow0 + ra) * K + k0 + ka];
    const float4 av1 = *(const float4*)&A [(arow0 + ra) * K + k0 + kb2];
    const float4 bv0 = *(const float4*)&Bw[(brow0 + ra) * K + k0 + ka];
    const float4 bv1 = *(const float4*)&Bw[(brow0 + ra) * K + k0 + kb2];
    __syncthreads();   // previous iteration's reads complete before overwrite
    As[ka + 0][ra] = av0.x; As[ka + 1][ra] = av0.y; As[ka + 2][ra] = av0.z; As[ka + 3][ra] = av0.w;
    As[kb2 + 0][ra] = av1.x; As[kb2 + 1][ra] = av1.y; As[kb2 + 2][ra] = av1.z; As[kb2 + 3][ra] = av1.w;
    Bs[ka + 0][ra] = bv0.x; Bs[ka + 1][ra] = bv0.y; Bs[ka + 2][ra] = bv0.z; Bs[ka + 3][ra] = bv0.w;
    Bs[kb2 + 0][ra] = bv1.x; Bs[kb2 + 1][ra] = bv1.y; Bs[kb2 + 2][ra] = bv1.z; Bs[kb2 + 3][ra] = bv1.w;
    __syncthreads();
    #pragma unroll
    for (int kk = 0; kk < 16; ++kk) {
      float a[8], bb[8];
      *(float4*)&a[0]  = *(const float4*)&As[kk][tr * 8];
      *(float4*)&a[4]  = *(const float4*)&As[kk][tr * 8 + 4];
      *(float4*)&bb[0] = *(const float4*)&Bs[kk][tc * 8];
      *(float4*)&bb[4] = *(const float4*)&Bs[kk][tc * 8 + 4];
      #pragma unroll
      for (int i = 0; i < 8; ++i)
        #pragma unroll
        for (int j = 0; j < 8; ++j)
          acc[i][j] = fmaf(a[i], bb[j], acc[i][j]);
    }
  }

  const int gr0 = (int)arow0 + tr * 8;
  const int gc0 = (int)brow0 + tc * 8;
  #pragma unroll
  for (int i = 0; i < 8; ++i) {
    const size_t off = (size_t)(gr0 + i) * N + gc0;
    #pragma unroll
    for (int jj = 0; jj < 2; ++jj) {
      const int j0 = jj * 4;
      float4 r;
      if constexpr (MODE == 0) {
        r.x = acc[i][j0]; r.y = acc[i][j0+1]; r.z = acc[i][j0+2]; r.w = acc[i][j0+3];
      } else if constexpr (MODE == 1) {
        const float4 xv = *(const float4*)&X[off + j0];
        r.x = acc[i][j0] + xv.x; r.y = acc[i][j0+1] + xv.y;
        r.z = acc[i][j0+2] + xv.z; r.w = acc[i][j0+3] + xv.w;
      } else {
        const float4 g = *(const float4*)&X[off + j0];
        r.x = (g.x / (1.f + expf(-g.x))) * acc[i][j0];
        r.y = (g.y / (1.f + expf(-g.y))) * acc[i][j0+1];
        r.z = (g.z / (1.f + expf(-g.z))) * acc[i][j0+2];
        r.w = (g.w / (1.f + expf(-g.w))) * acc[i][j0+3];
      }
      *(float4*)&C[off + j0] = r;
    }
  }
}

// ---------------------------------------------------------------------------
// Kernel 4: RoPE in-place on q [B,S,NH,D] and k [B,S,NKV,D]
// pair (i, i+32), angle = (pos_id + LCK) * 10000^(-i/32)
// BUGFIX r1->r2: sincosf's first out-pointer is SIN; use explicit sinf/cosf.
// ---------------------------------------------------------------------------
__global__ __launch_bounds__(256) void rope_kernel(
    float* __restrict__ qb, float* __restrict__ kb, const int* __restrict__ pid)
{
  const int idx = blockIdx.x * 256 + threadIdx.x;
  const int total_q = M_ * NH_ * 32;
  const int total_k = M_ * NKV_ * 32;
  if (idx >= total_q + total_k) return;

  float* base;
  int row, i;
  if (idx < total_q) {
    row = idx >> 10;               // / (NH*32)
    const int rem = idx & 1023;
    const int head = rem >> 5;
    i = rem & 31;
    base = qb + ((size_t)row * NH_ + head) * D_;
  } else {
    const int j = idx - total_q;
    row = j >> 8;                  // / (NKV*32)
    const int rem = j & 255;
    const int head = rem >> 5;
    i = rem & 31;
    base = kb + ((size_t)row * NKV_ + head) * D_;
  }
  const int pos = pid[row] + LCK_;
  const float invf = powf(10000.0f, -(float)i * (1.0f / 32.0f));
  const float ang = (float)pos * invf;
  const float c  = cosf(ang);
  const float sn = sinf(ang);
  const float x0 = base[i];
  const float x1 = base[i + 32];
  base[i]      = x0 * c - x1 * sn;
  base[i + 32] = x1 * c + x0 * sn;
}

// ---------------------------------------------------------------------------
// Kernel 5: flash-style attention.
//   s0 = q . cache_k[0]^T * scale  (causal over S keys)
//   sd[n] = q . extra_k[n][same position] * scale, n=0..2
//           extra_k = {cache_k[1], cache_k[2], current k (GQA h/4)}
//   softmax over S+3 logits; out = P[:, :S] @ cache_v[0] + sum_n p_n * extra_v[n]
// One block = (b, h, 64-row q tile). 256 threads, 4x4 micro-tiles.
// ---------------------------------------------------------------------------
__global__ __launch_bounds__(256) void attn_kernel(
    const float* __restrict__ qb, const float* __restrict__ kb, const float* __restrict__ vb,
    const float* __restrict__ ck, const float* __restrict__ cv,
    float* __restrict__ ao)
{
  const int bid = blockIdx.x;
  const int qt = bid & 15;
  const int bh = bid >> 4;
  const int h = bh & 31;
  const int b = bh >> 5;
  const int t = threadIdx.x;
  const int tr = t >> 4, tc = t & 15;
  const int m0 = tr * 4, n0 = tc * 4;
  const int qbase = qt * 64;

  __shared__ __align__(16) float Qs[64 * 68];   // [d][r], pre-scaled
  __shared__ __align__(16) float KPs[64 * 68];  // K tile [d][c], reused as P [c][m]
  __shared__ __align__(16) float Vs[64 * 68];   // [c][d]
  __shared__ float Ls[192];                     // extra logits

  const size_t bh_off = (size_t)b * NH_ + h;
  const float* K0 = ck + bh_off * S_ * D_;   // cache layer 0
  const float* V0 = cv + bh_off * S_ * D_;

  // stage Q transposed + scaled
  #pragma unroll
  for (int it = 0; it < 4; ++it) {
    const int f = t + it * 256;
    const int r = f >> 4;
    const int d4 = (f & 15) << 2;
    const float4 v = *(const float4*)&qb[(((size_t)(b * S_ + qbase + r)) * NH_ + h) * D_ + d4];
    Qs[(d4 + 0) * 68 + r] = v.x * 0.125f;
    Qs[(d4 + 1) * 68 + r] = v.y * 0.125f;
    Qs[(d4 + 2) * 68 + r] = v.z * 0.125f;
    Qs[(d4 + 3) * 68 + r] = v.w * 0.125f;
  }

  float m_r[4], l_r[4], O[4][4];
  #pragma unroll
  for (int i = 0; i < 4; ++i) {
    m_r[i] = -3.0e38f; l_r[i] = 0.f;
    #pragma unroll
    for (int j = 0; j < 4; ++j) O[i][j] = 0.f;
  }

  for (int kt = 0; kt <= qt; ++kt) {
    // stage K (transposed) and V (natural)
    #pragma unroll
    for (int it = 0; it < 4; ++it) {
      const int f = t + it * 256;
      const int r = f >> 4;
      const int d4 = (f & 15) << 2;
      const float4 kv = *(const float4*)&K0[((size_t)(kt * 64 + r)) * D_ + d4];
      KPs[(d4 + 0) * 68 + r] = kv.x;
      KPs[(d4 + 1) * 68 + r] = kv.y;
      KPs[(d4 + 2) * 68 + r] = kv.z;
      KPs[(d4 + 3) * 68 + r] = kv.w;
      const float4 vv = *(const float4*)&V0[((size_t)(kt * 64 + r)) * D_ + d4];
      *(float4*)&Vs[r * 68 + d4] = vv;
    }
    __syncthreads();

    // QK^T for this tile
    float s[4][4];
    #pragma unroll
    for (int i = 0; i < 4; ++i)
      #pragma unroll
      for (int j = 0; j < 4; ++j) s[i][j] = 0.f;
    #pragma unroll 16
    for (int d = 0; d < 64; ++d) {
      const float4 aq = *(const float4*)&Qs[d * 68 + m0];
      const float4 bk = *(const float4*)&KPs[d * 68 + n0];
      const float a4[4] = {aq.x, aq.y, aq.z, aq.w};
      const float b4[4] = {bk.x, bk.y, bk.z, bk.w};
      #pragma unroll
      for (int i = 0; i < 4; ++i)
        #pragma unroll
        for (int j = 0; j < 4; ++j)
          s[i][j] = fmaf(a4[i], b4[j], s[i][j]);
    }
    if (kt == qt) {  // causal mask inside the diagonal tile
      #pragma unroll
      for (int i = 0; i < 4; ++i)
        #pragma unroll
        for (int j = 0; j < 4; ++j)
          if (n0 + j > m0 + i) s[i][j] = -3.0e38f;
    }
    __syncthreads();  // all QK reads of KPs done before P overwrites it

    // online softmax update; write P into KPs as [c][m]
    #pragma unroll
    for (int i = 0; i < 4; ++i) {
      float rm = fmaxf(fmaxf(s[i][0], s[i][1]), fmaxf(s[i][2], s[i][3]));
      rm = fmaxf(rm, __shfl_xor(rm, 1));
      rm = fmaxf(rm, __shfl_xor(rm, 2));
      rm = fmaxf(rm, __shfl_xor(rm, 4));
      rm = fmaxf(rm, __shfl_xor(rm, 8));
      const float mnew = fmaxf(m_r[i], rm);
      const float alpha = __expf(m_r[i] - mnew);
      float p0 = __expf(s[i][0] - mnew);
      float p1 = __expf(s[i][1] - mnew);
      float p2 = __expf(s[i][2] - mnew);
      float p3 = __expf(s[i][3] - mnew);
      float rs = p0 + p1 + p2 + p3;
      rs += __shfl_xor(rs, 1);
      rs += __shfl_xor(rs, 2);
      rs += __shfl_xor(rs, 4);
      rs += __shfl_xor(rs, 8);
      l_r[i] = l_r[i] * alpha + rs;
      m_r[i] = mnew;
      #pragma unroll
      for (int j = 0; j < 4; ++j) O[i][j] *= alpha;
      KPs[(n0 + 0) * 68 + (m0 + i)] = p0;
      KPs[(n0 + 1) * 68 + (m0 + i)] = p1;
      KPs[(n0 + 2) * 68 + (m0 + i)] = p2;
      KPs[(n0 + 3) * 68 + (m0 + i)] = p3;
    }
    __syncthreads();  // P visible

    // O += P @ V
    #pragma unroll 16
    for (int c = 0; c < 64; ++c) {
      const float4 pp = *(const float4*)&KPs[c * 68 + m0];
      const float4 vv = *(const float4*)&Vs[c * 68 + n0];
      const float p4[4] = {pp.x, pp.y, pp.z, pp.w};
      const float v4[4] = {vv.x, vv.y, vv.z, vv.w};
      #pragma unroll
      for (int i = 0; i < 4; ++i)
        #pragma unroll
        for (int j = 0; j < 4; ++j)
          O[i][j] = fmaf(p4[i], v4[j], O[i][j]);
    }
    __syncthreads();  // PV reads done before next staging
  }

  // ---- 3 diagonal extras ----
  if (t < 192) {
    const int n = t >> 6;
    const int r = t & 63;
    const int qp = qbase + r;
    const float* kp;
    if (n < 2) kp = ck + ((((size_t)(n + 1) * B_ + b) * NH_ + h) * S_ + qp) * D_;
    else       kp = kb + (((size_t)(b * S_ + qp)) * NKV_ + (h >> 2)) * D_;
    float e = 0.f;
    #pragma unroll 16
    for (int d = 0; d < 64; ++d) e = fmaf(Qs[d * 68 + r], kp[d], e);
    Ls[n * 64 + r] = e;
  }
  __syncthreads();

  #pragma unroll
  for (int i = 0; i < 4; ++i) {
    const int r = m0 + i;
    const int qp = qbase + r;
    const float e0 = Ls[r], e1 = Ls[64 + r], e2 = Ls[128 + r];
    const float mnew = fmaxf(fmaxf(m_r[i], e0), fmaxf(e1, e2));
    const float alpha = __expf(m_r[i] - mnew);
    const float p0 = __expf(e0 - mnew);
    const float p1 = __expf(e1 - mnew);
    const float p2 = __expf(e2 - mnew);
    l_r[i] = l_r[i] * alpha + p0 + p1 + p2;
    const float4 v0 = *(const float4*)&cv[((((size_t)1 * B_ + b) * NH_ + h) * S_ + qp) * D_ + n0];
    const float4 v1 = *(const float4*)&cv[((((size_t)2 * B_ + b) * NH_ + h) * S_ + qp) * D_ + n0];
    const float4 v2 = *(const float4*)&vb[(((size_t)(b * S_ + qp)) * NKV_ + (h >> 2)) * D_ + n0];
    const float inv = 1.0f / l_r[i];
    float4 o;
    o.x = (O[i][0] * alpha + p0 * v0.x + p1 * v1.x + p2 * v2.x) * inv;
    o.y = (O[i][1] * alpha + p0 * v0.y + p1 * v1.y + p2 * v2.y) * inv;
    o.z = (O[i][2] * alpha + p0 * v0.z + p1 * v1.z + p2 * v2.z) * inv;
    o.w = (O[i][3] * alpha + p0 * v0.w + p1 * v1.w + p2 * v2.w) * inv;
    *(float4*)&ao[(((size_t)(b * S_ + qp)) * NH_ + h) * D_ + n0] = o;
  }
}

// ---------------------------------------------------------------------------
extern "C" void kernel_launch(void* const* d_in, const int* in_sizes, int n_in,
                              void* d_out, int out_size, void* d_ws, size_t ws_size,
                              hipStream_t stream)
{
  const float* input_emb = (const float*)d_in[0];
  const float* hidden    = (const float*)d_in[1];
  const float* cache_k   = (const float*)d_in[2];
  const float* cache_v   = (const float*)d_in[3];
  // d_in[4] = attention_mask: exactly lower-triangular causal -> applied analytically
  const int*   pos_ids   = (const int*)d_in[5];
  const float* wq = (const float*)d_in[6];
  const float* wk = (const float*)d_in[7];
  const float* wv = (const float*)d_in[8];
  const float* wo = (const float*)d_in[9];
  const float* wg = (const float*)d_in[10];
  const float* wu = (const float*)d_in[11];
  const float* wd = (const float*)d_in[12];
  const float* w_hidden_norm = (const float*)d_in[13];
  const float* w_input_ln    = (const float*)d_in[14];
  const float* w_post_ln     = (const float*)d_in[15];
  float* out = (float*)d_out;

  // workspace layout with lifetime-based aliasing (peak 112 MB):
  //   x  [0,  32MB)  : live norm_concat -> v GEMM
  //   qb [32, 48MB)  : live q GEMM -> attn
  //   kb [48, 52MB), vb [52, 56MB) : live -> attn
  //   ao [0,  16MB)  : aliases x;  live attn -> wo GEMM
  //   h2 [16, 32MB)  : aliases x;  live wo GEMM -> final GEMM
  //   hn [32, 48MB)  : aliases qb; live rmsnorm -> up GEMM
  //   gb [48, 112MB) : aliases kb/vb; live gate GEMM -> final GEMM
  float* ws = (float*)d_ws;
  float* x  = ws;
  float* qb = ws + (size_t)(32u << 20) / 4;
  float* kb = ws + (size_t)(48u << 20) / 4;
  float* vb = ws + (size_t)(52u << 20) / 4;
  float* ao = ws;
  float* h2 = ws + (size_t)(16u << 20) / 4;
  float* hn = ws + (size_t)(32u << 20) / 4;
  float* gb = ws + (size_t)(48u << 20) / 4;

  // 1. norms + concat
  norm_concat_kernel<<<M_, 256, 0, stream>>>(input_emb, hidden, w_input_ln, w_hidden_norm, x);
  // 2. QKV projections
  gemm_nt_kernel<0><<<dim3(16, 16), 256, 0, stream>>>(x, wq, qb, nullptr, M_, 2048, 4096);
  gemm_nt_kernel<0><<<dim3(4, 16), 256, 0, stream>>>(x, wk, kb, nullptr, M_, 512, 4096);
  gemm_nt_kernel<0><<<dim3(4, 16), 256, 0, stream>>>(x, wv, vb, nullptr, M_, 512, 4096);
  // 3. RoPE (in-place on q, k)
  {
    const int total = M_ * NH_ * 32 + M_ * NKV_ * 32;
    rope_kernel<<<(total + 255) / 256, 256, 0, stream>>>(qb, kb, pos_ids);
  }
  // 4. attention (reads qb/kb/vb + caches, writes ao; x is dead by now)
  attn_kernel<<<B_ * NH_ * (S_ / 64), 256, 0, stream>>>(qb, kb, vb, cache_k, cache_v, ao);
  // 5. output projection + residual -> h2
  gemm_nt_kernel<1><<<dim3(16, 16), 256, 0, stream>>>(ao, wo, h2, hidden, M_, 2048, 2048);
  // 6. post-attention RMSNorm (qb dead -> hn aliases it)
  rmsnorm_kernel<<<M_, 256, 0, stream>>>(h2, w_post_ln, hn);
  // 7. SwiGLU MLP: gate, then silu(gate)*up (in-place on gb), then down + residual
  gemm_nt_kernel<0><<<dim3(64, 16), 256, 0, stream>>>(hn, wg, gb, nullptr, M_, 8192, 2048);
  gemm_nt_kernel<2><<<dim3(64, 16), 256, 0, stream>>>(hn, wu, gb, gb, M_, 8192, 2048);
  gemm_nt_kernel<1><<<dim3(16, 16), 256, 0, stream>>>(gb, wd, out, h2, M_, 2048, 8192);
}

// Round 3
// 1522.980 us; speedup vs baseline: 3.8777x; 3.8777x over previous
//
#include <hip/hip_runtime.h>
#include <math.h>

#define B_   2
#define S_   1024
#define H_   2048
#define NH_  32
#define NKV_ 8
#define D_   64
#define I_   8192
#define LCK_ 3
#define M_   (B_ * S_)   // 2048 token rows

typedef unsigned short u16;
typedef unsigned int   u32;
typedef __attribute__((ext_vector_type(8))) short bf16x8;   // 8 bf16 (4 VGPRs) - guide-verified frag type
typedef __attribute__((ext_vector_type(4))) float f32x4;
typedef __attribute__((ext_vector_type(2))) unsigned int u32x2;

// f32 -> bf16 round-to-nearest-even (finite inputs)
__device__ __forceinline__ u16 f2b(float f) {
  u32 u = __float_as_uint(f);
  u += 0x7fffu + ((u >> 16) & 1u);
  return (u16)(u >> 16);
}
__device__ __forceinline__ float b2f(u16 h) { return __uint_as_float(((u32)h) << 16); }

__device__ __forceinline__ void st_bf4(u16* p, float a, float b, float c, float d) {
  u32x2 v;
  v.x = (u32)f2b(a) | ((u32)f2b(b) << 16);
  v.y = (u32)f2b(c) | ((u32)f2b(d) << 16);
  *(u32x2*)p = v;
}

// async global->LDS, 16B per lane; LDS dest = wave-uniform base + lane*16
__device__ __forceinline__ void async16(const void* g, void* l) {
  __builtin_amdgcn_global_load_lds(
      (const __attribute__((address_space(1))) unsigned int*)(uintptr_t)g,
      (__attribute__((address_space(3))) unsigned int*)(unsigned int)(uintptr_t)l,
      16, 0, 0);
}

// ---------------------------------------------------------------------------
// Kernel 1: fused RMSNorm(emb)+RMSNorm(hidden) -> x = concat([e,h]) as BF16
// ---------------------------------------------------------------------------
__global__ __launch_bounds__(256) void norm_concat_kernel(
    const float* __restrict__ emb, const float* __restrict__ hid,
    const float* __restrict__ w_e, const float* __restrict__ w_h,
    u16* __restrict__ x)
{
  const int row = blockIdx.x;
  const int t = threadIdx.x;
  const float* e = emb + (size_t)row * H_;
  const float* h = hid + (size_t)row * H_;

  const float4 ev0 = *(const float4*)&e[t * 4];
  const float4 ev1 = *(const float4*)&e[t * 4 + 1024];
  const float4 hv0 = *(const float4*)&h[t * 4];
  const float4 hv1 = *(const float4*)&h[t * 4 + 1024];

  float se = ev0.x*ev0.x + ev0.y*ev0.y + ev0.z*ev0.z + ev0.w*ev0.w
           + ev1.x*ev1.x + ev1.y*ev1.y + ev1.z*ev1.z + ev1.w*ev1.w;
  float sh = hv0.x*hv0.x + hv0.y*hv0.y + hv0.z*hv0.z + hv0.w*hv0.w
           + hv1.x*hv1.x + hv1.y*hv1.y + hv1.z*hv1.z + hv1.w*hv1.w;

  #pragma unroll
  for (int m = 1; m < 64; m <<= 1) {
    se += __shfl_xor(se, m);
    sh += __shfl_xor(sh, m);
  }
  __shared__ float red[8];
  const int wv = t >> 6;
  if ((t & 63) == 0) { red[wv] = se; red[4 + wv] = sh; }
  __syncthreads();
  se = red[0] + red[1] + red[2] + red[3];
  sh = red[4] + red[5] + red[6] + red[7];

  const float re = 1.0f / sqrtf(se * (1.0f / H_) + 1e-6f);
  const float rh = 1.0f / sqrtf(sh * (1.0f / H_) + 1e-6f);

  const float4 we0 = *(const float4*)&w_e[t * 4];
  const float4 we1 = *(const float4*)&w_e[t * 4 + 1024];
  const float4 wh0 = *(const float4*)&w_h[t * 4];
  const float4 wh1 = *(const float4*)&w_h[t * 4 + 1024];

  u16* xr = x + (size_t)row * (2 * H_);
  st_bf4(&xr[t * 4],        ev0.x*re*we0.x, ev0.y*re*we0.y, ev0.z*re*we0.z, ev0.w*re*we0.w);
  st_bf4(&xr[t * 4 + 1024], ev1.x*re*we1.x, ev1.y*re*we1.y, ev1.z*re*we1.z, ev1.w*re*we1.w);
  st_bf4(&xr[2048 + t * 4],        hv0.x*rh*wh0.x, hv0.y*rh*wh0.y, hv0.z*rh*wh0.z, hv0.w*rh*wh0.w);
  st_bf4(&xr[2048 + t * 4 + 1024], hv1.x*rh*wh1.x, hv1.y*rh*wh1.y, hv1.z*rh*wh1.z, hv1.w*rh*wh1.w);
}

// ---------------------------------------------------------------------------
// Kernel 2: RMSNorm f32 in -> BF16 out (post-attention norm)
// ---------------------------------------------------------------------------
__global__ __launch_bounds__(256) void rmsnorm_kernel(
    const float* __restrict__ in, const float* __restrict__ w, u16* __restrict__ outp)
{
  const int row = blockIdx.x;
  const int t = threadIdx.x;
  const float* p = in + (size_t)row * H_;
  const float4 v0 = *(const float4*)&p[t * 4];
  const float4 v1 = *(const float4*)&p[t * 4 + 1024];
  float s = v0.x*v0.x + v0.y*v0.y + v0.z*v0.z + v0.w*v0.w
          + v1.x*v1.x + v1.y*v1.y + v1.z*v1.z + v1.w*v1.w;
  #pragma unroll
  for (int m = 1; m < 64; m <<= 1) s += __shfl_xor(s, m);
  __shared__ float red[4];
  const int wv = t >> 6;
  if ((t & 63) == 0) red[wv] = s;
  __syncthreads();
  s = red[0] + red[1] + red[2] + red[3];
  const float rs = 1.0f / sqrtf(s * (1.0f / H_) + 1e-6f);

  const float4 w0 = *(const float4*)&w[t * 4];
  const float4 w1 = *(const float4*)&w[t * 4 + 1024];
  u16* orow = outp + (size_t)row * H_;
  st_bf4(&orow[t * 4],        v0.x*rs*w0.x, v0.y*rs*w0.y, v0.z*rs*w0.z, v0.w*rs*w0.w);
  st_bf4(&orow[t * 4 + 1024], v1.x*rs*w1.x, v1.y*rs*w1.y, v1.z*rs*w1.z, v1.w*rs*w1.w);
}

// ---------------------------------------------------------------------------
// Kernel 3: weight f32->bf16 converters
// convert6: wq|wk|wv|wo|wg|wu packed contiguously into dst (element order)
// ---------------------------------------------------------------------------
__global__ __launch_bounds__(256) void convert6_kernel(
    const float* __restrict__ wq, const float* __restrict__ wk, const float* __restrict__ wv,
    const float* __restrict__ wo, const float* __restrict__ wg, const float* __restrict__ wu,
    u16* __restrict__ dst)
{
  const size_t i8 = ((size_t)blockIdx.x * 256 + threadIdx.x) * 8;
  const float* s; size_t base;
  if      (i8 <  8388608) { s = wq; base = 0; }
  else if (i8 < 10485760) { s = wk; base = 8388608; }
  else if (i8 < 12582912) { s = wv; base = 10485760; }
  else if (i8 < 16777216) { s = wo; base = 12582912; }
  else if (i8 < 33554432) { s = wg; base = 16777216; }
  else                    { s = wu; base = 33554432; }
  const float4 a = *(const float4*)&s[i8 - base];
  const float4 b = *(const float4*)&s[i8 - base + 4];
  bf16x8 r;
  r[0] = (short)f2b(a.x); r[1] = (short)f2b(a.y); r[2] = (short)f2b(a.z); r[3] = (short)f2b(a.w);
  r[4] = (short)f2b(b.x); r[5] = (short)f2b(b.y); r[6] = (short)f2b(b.z); r[7] = (short)f2b(b.w);
  *(bf16x8*)&dst[i8] = r;
}

__global__ __launch_bounds__(256) void convert1_kernel(
    const float* __restrict__ src, u16* __restrict__ dst)
{
  const size_t i8 = ((size_t)blockIdx.x * 256 + threadIdx.x) * 8;
  const float4 a = *(const float4*)&src[i8];
  const float4 b = *(const float4*)&src[i8 + 4];
  bf16x8 r;
  r[0] = (short)f2b(a.x); r[1] = (short)f2b(a.y); r[2] = (short)f2b(a.z); r[3] = (short)f2b(a.w);
  r[4] = (short)f2b(b.x); r[5] = (short)f2b(b.y); r[6] = (short)f2b(b.z); r[7] = (short)f2b(b.w);
  *(bf16x8*)&dst[i8] = r;
}

// ---------------------------------------------------------------------------
// Kernel 4: BF16 MFMA NT-GEMM (m97 structure)  C[M,N] = A[M,K] * Bw[N,K]^T
// 128x128 tile, BK=32, 256 thr (4 waves, 2x2), wave = 4x4 of 16x16x32 MFMA.
// global_load_lds width=16 into unpadded [128][32] bf16 LDS; 2-barrier K-loop.
// MODE 0: f32 C = acc
// MODE 1: f32 C = acc + Xf32      (residual; C/X may alias other buffers, not each other)
// MODE 2: bf16 C = acc            (gate)
// MODE 3: bf16 C = silu(Xbf16) * acc   (up: X = gate buffer)
// ---------------------------------------------------------------------------
template <int MODE>
__global__ __launch_bounds__(256) void gemm_bf16_kernel(
    const u16* __restrict__ A, const u16* __restrict__ Bw,
    void* Cv, const void* Xv, int M, int N, int K)
{
  __shared__ __align__(16) u16 As[128 * 32];
  __shared__ __align__(16) u16 Bs[128 * 32];
  const int t = threadIdx.x;
  const int lane = t & 63;
  const int w = t >> 6;            // wave 0..3
  const int wr = w >> 1, wc = w & 1;
  const int row0 = blockIdx.y * 128;
  const int col0 = blockIdx.x * 128;

  f32x4 acc[4][4];
  #pragma unroll
  for (int i = 0; i < 4; ++i)
    #pragma unroll
    for (int j = 0; j < 4; ++j)
      #pragma unroll
      for (int r = 0; r < 4; ++r) acc[i][j][r] = 0.f;

  // staging: wave w loads rows [w*32, w*32+32) of each 128x32 tile
  // lane l -> row w*32 + (l>>2) (+16 on 2nd call), 16B chunk (l&3)*8 bf16
  const int srow = lane >> 2;
  const int skc  = (lane & 3) * 8;
  const u16* Ag = A  + (size_t)(row0 + w * 32 + srow) * K + skc;
  const u16* Bg = Bw + (size_t)(col0 + w * 32 + srow) * K + skc;
  u16* AsW = &As[w * 32 * 32];
  u16* BsW = &Bs[w * 32 * 32];

  // MFMA fragment read coords (A[m=lane&15][k=(lane>>4)*8+j])
  const int fr = lane & 15;
  const int fq = (lane >> 4) * 8;

  for (int k0 = 0; k0 < K; k0 += 32) {
    __syncthreads();   // previous iter's ds_reads complete (lgkmcnt drained by barrier)
    async16(Ag + k0,                  AsW);
    async16(Ag + k0 + (size_t)16 * K, AsW + 16 * 32);
    async16(Bg + k0,                  BsW);
    async16(Bg + k0 + (size_t)16 * K, BsW + 16 * 32);
    __syncthreads();   // vmcnt(0) drain: staged data visible

    bf16x8 af[4], bfr[4];
    #pragma unroll
    for (int ti = 0; ti < 4; ++ti)
      af[ti] = *(const bf16x8*)&As[(wr * 64 + ti * 16 + fr) * 32 + fq];
    #pragma unroll
    for (int tj = 0; tj < 4; ++tj)
      bfr[tj] = *(const bf16x8*)&Bs[(wc * 64 + tj * 16 + fr) * 32 + fq];
    #pragma unroll
    for (int ti = 0; ti < 4; ++ti)
      #pragma unroll
      for (int tj = 0; tj < 4; ++tj)
        acc[ti][tj] = __builtin_amdgcn_mfma_f32_16x16x32_bf16(af[ti], bfr[tj], acc[ti][tj], 0, 0, 0);
  }

  // epilogue: C/D layout col=lane&15, row=(lane>>4)*4+reg  [m89/m91 verified]
  float* Cf = (float*)Cv;
  u16*  Cb = (u16*)Cv;
  const float* Xf = (const float*)Xv;
  const u16*  Xb = (const u16*)Xv;
  const int rbase = (lane >> 4) * 4;
  const int cofs  = lane & 15;
  #pragma unroll
  for (int ti = 0; ti < 4; ++ti) {
    #pragma unroll
    for (int r = 0; r < 4; ++r) {
      const int gr = row0 + wr * 64 + ti * 16 + rbase + r;
      #pragma unroll
      for (int tj = 0; tj < 4; ++tj) {
        const int gc = col0 + wc * 64 + tj * 16 + cofs;
        const size_t off = (size_t)gr * N + gc;
        const float v = acc[ti][tj][r];
        if constexpr (MODE == 0) {
          Cf[off] = v;
        } else if constexpr (MODE == 1) {
          Cf[off] = v + Xf[off];
        } else if constexpr (MODE == 2) {
          Cb[off] = f2b(v);
        } else {
          const float g = b2f(Xb[off]);
          Cb[off] = f2b((g / (1.f + __expf(-g))) * v);
        }
      }
    }
  }
}

// ---------------------------------------------------------------------------
// Kernel 5: RoPE in-place on f32 q [B,S,NH,D] and k [B,S,NKV,D]
// ---------------------------------------------------------------------------
__global__ __launch_bounds__(256) void rope_kernel(
    float* __restrict__ qb, float* __restrict__ kb, const int* __restrict__ pid)
{
  const int idx = blockIdx.x * 256 + threadIdx.x;
  const int total_q = M_ * NH_ * 32;
  const int total_k = M_ * NKV_ * 32;
  if (idx >= total_q + total_k) return;

  float* base;
  int row, i;
  if (idx < total_q) {
    row = idx >> 10;
    const int rem = idx & 1023;
    const int head = rem >> 5;
    i = rem & 31;
    base = qb + ((size_t)row * NH_ + head) * D_;
  } else {
    const int j = idx - total_q;
    row = j >> 8;
    const int rem = j & 255;
    const int head = rem >> 5;
    i = rem & 31;
    base = kb + ((size_t)row * NKV_ + head) * D_;
  }
  const int pos = pid[row] + LCK_;
  const float invf = powf(10000.0f, -(float)i * (1.0f / 32.0f));
  const float ang = (float)pos * invf;
  const float c  = cosf(ang);
  const float sn = sinf(ang);
  const float x0 = base[i];
  const float x1 = base[i + 32];
  base[i]      = x0 * c - x1 * sn;
  base[i + 32] = x1 * c + x0 * sn;
}

// ---------------------------------------------------------------------------
// Kernel 6: flash-style attention (f32 compute), BF16 output for wo GEMM.
// ---------------------------------------------------------------------------
__global__ __launch_bounds__(256) void attn_kernel(
    const float* __restrict__ qb, const float* __restrict__ kb, const float* __restrict__ vb,
    const float* __restrict__ ck, const float* __restrict__ cv,
    u16* __restrict__ ao)
{
  const int bid = blockIdx.x;
  const int qt = bid & 15;
  const int bh = bid >> 4;
  const int h = bh & 31;
  const int b = bh >> 5;
  const int t = threadIdx.x;
  const int tr = t >> 4, tc = t & 15;
  const int m0 = tr * 4, n0 = tc * 4;
  const int qbase = qt * 64;

  __shared__ __align__(16) float Qs[64 * 68];   // [d][r], pre-scaled
  __shared__ __align__(16) float KPs[64 * 68];  // K tile [d][c], reused as P [c][m]
  __shared__ __align__(16) float Vs[64 * 68];   // [c][d]
  __shared__ float Ls[192];

  const size_t bh_off = (size_t)b * NH_ + h;
  const float* K0 = ck + bh_off * S_ * D_;
  const float* V0 = cv + bh_off * S_ * D_;

  #pragma unroll
  for (int it = 0; it < 4; ++it) {
    const int f = t + it * 256;
    const int r = f >> 4;
    const int d4 = (f & 15) << 2;
    const float4 v = *(const float4*)&qb[(((size_t)(b * S_ + qbase + r)) * NH_ + h) * D_ + d4];
    Qs[(d4 + 0) * 68 + r] = v.x * 0.125f;
    Qs[(d4 + 1) * 68 + r] = v.y * 0.125f;
    Qs[(d4 + 2) * 68 + r] = v.z * 0.125f;
    Qs[(d4 + 3) * 68 + r] = v.w * 0.125f;
  }

  float m_r[4], l_r[4], O[4][4];
  #pragma unroll
  for (int i = 0; i < 4; ++i) {
    m_r[i] = -3.0e38f; l_r[i] = 0.f;
    #pragma unroll
    for (int j = 0; j < 4; ++j) O[i][j] = 0.f;
  }

  for (int kt = 0; kt <= qt; ++kt) {
    #pragma unroll
    for (int it = 0; it < 4; ++it) {
      const int f = t + it * 256;
      const int r = f >> 4;
      const int d4 = (f & 15) << 2;
      const float4 kv = *(const float4*)&K0[((size_t)(kt * 64 + r)) * D_ + d4];
      KPs[(d4 + 0) * 68 + r] = kv.x;
      KPs[(d4 + 1) * 68 + r] = kv.y;
      KPs[(d4 + 2) * 68 + r] = kv.z;
      KPs[(d4 + 3) * 68 + r] = kv.w;
      const float4 vv = *(const float4*)&V0[((size_t)(kt * 64 + r)) * D_ + d4];
      *(float4*)&Vs[r * 68 + d4] = vv;
    }
    __syncthreads();

    float s[4][4];
    #pragma unroll
    for (int i = 0; i < 4; ++i)
      #pragma unroll
      for (int j = 0; j < 4; ++j) s[i][j] = 0.f;
    #pragma unroll 16
    for (int d = 0; d < 64; ++d) {
      const float4 aq = *(const float4*)&Qs[d * 68 + m0];
      const float4 bk = *(const float4*)&KPs[d * 68 + n0];
      const float a4[4] = {aq.x, aq.y, aq.z, aq.w};
      const float b4[4] = {bk.x, bk.y, bk.z, bk.w};
      #pragma unroll
      for (int i = 0; i < 4; ++i)
        #pragma unroll
        for (int j = 0; j < 4; ++j)
          s[i][j] = fmaf(a4[i], b4[j], s[i][j]);
    }
    if (kt == qt) {
      #pragma unroll
      for (int i = 0; i < 4; ++i)
        #pragma unroll
        for (int j = 0; j < 4; ++j)
          if (n0 + j > m0 + i) s[i][j] = -3.0e38f;
    }
    __syncthreads();

    #pragma unroll
    for (int i = 0; i < 4; ++i) {
      float rm = fmaxf(fmaxf(s[i][0], s[i][1]), fmaxf(s[i][2], s[i][3]));
      rm = fmaxf(rm, __shfl_xor(rm, 1));
      rm = fmaxf(rm, __shfl_xor(rm, 2));
      rm = fmaxf(rm, __shfl_xor(rm, 4));
      rm = fmaxf(rm, __shfl_xor(rm, 8));
      const float mnew = fmaxf(m_r[i], rm);
      const float alpha = __expf(m_r[i] - mnew);
      float p0 = __expf(s[i][0] - mnew);
      float p1 = __expf(s[i][1] - mnew);
      float p2 = __expf(s[i][2] - mnew);
      float p3 = __expf(s[i][3] - mnew);
      float rs = p0 + p1 + p2 + p3;
      rs += __shfl_xor(rs, 1);
      rs += __shfl_xor(rs, 2);
      rs += __shfl_xor(rs, 4);
      rs += __shfl_xor(rs, 8);
      l_r[i] = l_r[i] * alpha + rs;
      m_r[i] = mnew;
      #pragma unroll
      for (int j = 0; j < 4; ++j) O[i][j] *= alpha;
      KPs[(n0 + 0) * 68 + (m0 + i)] = p0;
      KPs[(n0 + 1) * 68 + (m0 + i)] = p1;
      KPs[(n0 + 2) * 68 + (m0 + i)] = p2;
      KPs[(n0 + 3) * 68 + (m0 + i)] = p3;
    }
    __syncthreads();

    #pragma unroll 16
    for (int c = 0; c < 64; ++c) {
      const float4 pp = *(const float4*)&KPs[c * 68 + m0];
      const float4 vv = *(const float4*)&Vs[c * 68 + n0];
      const float p4[4] = {pp.x, pp.y, pp.z, pp.w};
      const float v4[4] = {vv.x, vv.y, vv.z, vv.w};
      #pragma unroll
      for (int i = 0; i < 4; ++i)
        #pragma unroll
        for (int j = 0; j < 4; ++j)
          O[i][j] = fmaf(p4[i], v4[j], O[i][j]);
    }
    __syncthreads();
  }

  if (t < 192) {
    const int n = t >> 6;
    const int r = t & 63;
    const int qp = qbase + r;
    const float* kp;
    if (n < 2) kp = ck + ((((size_t)(n + 1) * B_ + b) * NH_ + h) * S_ + qp) * D_;
    else       kp = kb + (((size_t)(b * S_ + qp)) * NKV_ + (h >> 2)) * D_;
    float e = 0.f;
    #pragma unroll 16
    for (int d = 0; d < 64; ++d) e = fmaf(Qs[d * 68 + r], kp[d], e);
    Ls[n * 64 + r] = e;
  }
  __syncthreads();

  #pragma unroll
  for (int i = 0; i < 4; ++i) {
    const int r = m0 + i;
    const int qp = qbase + r;
    const float e0 = Ls[r], e1 = Ls[64 + r], e2 = Ls[128 + r];
    const float mnew = fmaxf(fmaxf(m_r[i], e0), fmaxf(e1, e2));
    const float alpha = __expf(m_r[i] - mnew);
    const float p0 = __expf(e0 - mnew);
    const float p1 = __expf(e1 - mnew);
    const float p2 = __expf(e2 - mnew);
    l_r[i] = l_r[i] * alpha + p0 + p1 + p2;
    const float4 v0 = *(const float4*)&cv[((((size_t)1 * B_ + b) * NH_ + h) * S_ + qp) * D_ + n0];
    const float4 v1 = *(const float4*)&cv[((((size_t)2 * B_ + b) * NH_ + h) * S_ + qp) * D_ + n0];
    const float4 v2 = *(const float4*)&vb[(((size_t)(b * S_ + qp)) * NKV_ + (h >> 2)) * D_ + n0];
    const float inv = 1.0f / l_r[i];
    st_bf4(&ao[(((size_t)(b * S_ + qp)) * NH_ + h) * D_ + n0],
           (O[i][0] * alpha + p0 * v0.x + p1 * v1.x + p2 * v2.x) * inv,
           (O[i][1] * alpha + p0 * v0.y + p1 * v1.y + p2 * v2.y) * inv,
           (O[i][2] * alpha + p0 * v0.z + p1 * v1.z + p2 * v2.z) * inv,
           (O[i][3] * alpha + p0 * v0.w + p1 * v1.w + p2 * v2.w) * inv);
  }
}

// ---------------------------------------------------------------------------
extern "C" void kernel_launch(void* const* d_in, const int* in_sizes, int n_in,
                              void* d_out, int out_size, void* d_ws, size_t ws_size,
                              hipStream_t stream)
{
  const float* input_emb = (const float*)d_in[0];
  const float* hidden    = (const float*)d_in[1];
  const float* cache_k   = (const float*)d_in[2];
  const float* cache_v   = (const float*)d_in[3];
  const int*   pos_ids   = (const int*)d_in[5];
  const float* wq = (const float*)d_in[6];
  const float* wk = (const float*)d_in[7];
  const float* wv = (const float*)d_in[8];
  const float* wo = (const float*)d_in[9];
  const float* wg = (const float*)d_in[10];
  const float* wu = (const float*)d_in[11];
  const float* wd = (const float*)d_in[12];
  const float* w_hidden_norm = (const float*)d_in[13];
  const float* w_input_ln    = (const float*)d_in[14];
  const float* w_post_ln     = (const float*)d_in[15];
  float* out = (float*)d_out;

  // Workspace (byte offsets), peak 160 MiB, lifetime-aliased:
  //  [0,16.8M)    wq_b    -> dead after q GEMM;   reused by gub (up out)
  //  [16.8,21M)   wk_b    -> dead after k GEMM
  //  [21,25.2M)   wv_b    -> dead after v GEMM
  //  [25.2,33.6M) wo_b    -> dead after wo GEMM
  //  [33.6,67.1M) wg_b    -> dead after gate GEMM
  //  [67.1,100.7M)wu_b    -> dead after up GEMM
  //  [100.7,117.4M) x_b   -> dead after v GEMM;   reused by hn
  //  [117.4,134.2M) qb f32 -> dead after attn ┐
  //  [134.2,138.4M) kb f32 -> dead after attn │ reused by gb_b (gate out, 33.5M),
  //  [138.4,142.6M) vb f32 -> dead after attn │ then by wd_b after up GEMM
  //  [142.6,151M)   ao b16 -> dead after wo   ┘
  //  [151,167.8M)   h2 f32 -> live to the end
  char* wsb = (char*)d_ws;
  u16*   wq_b = (u16*)(wsb + 0);
  u16*   wall = wq_b;                          // convert6 contiguous dst
  u16*   wk_b = (u16*)(wsb + 16777216);
  u16*   wv_b = (u16*)(wsb + 20971520);
  u16*   wo_b = (u16*)(wsb + 25165824);
  u16*   wg_b = (u16*)(wsb + 33554432);
  u16*   wu_b = (u16*)(wsb + 67108864);
  u16*   xb   = (u16*)(wsb + 100663296);
  float* qb   = (float*)(wsb + 117440512);
  float* kb   = (float*)(wsb + 134217728);
  float* vb   = (float*)(wsb + 138412032);
  u16*   ao   = (u16*)(wsb + 142606336);
  float* h2   = (float*)(wsb + 150994944);
  u16*   hn   = (u16*)(wsb + 100663296);       // alias x_b
  u16*   gbb  = (u16*)(wsb + 117440512);       // alias qb/kb/vb/ao
  u16*   gub  = (u16*)(wsb + 0);               // alias wq_b..wo_b
  u16*   wd_b = (u16*)(wsb + 117440512);       // alias gbb (after up GEMM)

  // 1. weights -> bf16 (wq..wu, 50.3M elements)
  convert6_kernel<<<24576, 256, 0, stream>>>(wq, wk, wv, wo, wg, wu, wall);
  // 2. fused norms + concat -> bf16 x
  norm_concat_kernel<<<M_, 256, 0, stream>>>(input_emb, hidden, w_input_ln, w_hidden_norm, xb);
  // 3. QKV projections (bf16 MFMA, f32 out)
  gemm_bf16_kernel<0><<<dim3(16, 16), 256, 0, stream>>>(xb, wq_b, qb, nullptr, M_, 2048, 4096);
  gemm_bf16_kernel<0><<<dim3(4, 16), 256, 0, stream>>>(xb, wk_b, kb, nullptr, M_, 512, 4096);
  gemm_bf16_kernel<0><<<dim3(4, 16), 256, 0, stream>>>(xb, wv_b, vb, nullptr, M_, 512, 4096);
  // 4. RoPE in-place (f32)
  {
    const int total = M_ * NH_ * 32 + M_ * NKV_ * 32;
    rope_kernel<<<(total + 255) / 256, 256, 0, stream>>>(qb, kb, pos_ids);
  }
  // 5. attention -> bf16 ao
  attn_kernel<<<B_ * NH_ * (S_ / 64), 256, 0, stream>>>(qb, kb, vb, cache_k, cache_v, ao);
  // 6. output projection + residual(hidden) -> f32 h2
  gemm_bf16_kernel<1><<<dim3(16, 16), 256, 0, stream>>>(ao, wo_b, h2, hidden, M_, 2048, 2048);
  // 7. post-attention RMSNorm -> bf16 hn
  rmsnorm_kernel<<<M_, 256, 0, stream>>>(h2, w_post_ln, hn);
  // 8. gate GEMM -> bf16 gbb
  gemm_bf16_kernel<2><<<dim3(64, 16), 256, 0, stream>>>(hn, wg_b, gbb, nullptr, M_, 8192, 2048);
  // 9. up GEMM, epilogue silu(gate)*up -> bf16 gub
  gemm_bf16_kernel<3><<<dim3(64, 16), 256, 0, stream>>>(hn, wu_b, gub, gbb, M_, 8192, 2048);
  // 10. wd -> bf16 (into gbb's region, now dead)
  convert1_kernel<<<8192, 256, 0, stream>>>(wd, wd_b);
  // 11. down GEMM + residual(h2) -> out f32
  gemm_bf16_kernel<1><<<dim3(16, 16), 256, 0, stream>>>(gub, wd_b, out, h2, M_, 2048, 8192);
}

// Round 4
// 1064.503 us; speedup vs baseline: 5.5478x; 1.4307x over previous
//
#include <hip/hip_runtime.h>
#include <math.h>

#define B_   2
#define S_   1024
#define H_   2048
#define NH_  32
#define NKV_ 8
#define D_   64
#define I_   8192
#define LCK_ 3
#define M_   (B_ * S_)   // 2048 token rows

typedef unsigned short u16;
typedef unsigned int   u32;
typedef __attribute__((ext_vector_type(8))) short bf16x8;   // 8 bf16 (4 VGPRs)
typedef __attribute__((ext_vector_type(4))) float f32x4;
typedef __attribute__((ext_vector_type(2))) unsigned int u32x2;

// f32 -> bf16 round-to-nearest-even (finite inputs)
__device__ __forceinline__ u16 f2b(float f) {
  u32 u = __float_as_uint(f);
  u += 0x7fffu + ((u >> 16) & 1u);
  return (u16)(u >> 16);
}
__device__ __forceinline__ float b2f(u16 h) { return __uint_as_float(((u32)h) << 16); }

__device__ __forceinline__ void st_bf4(u16* p, float a, float b, float c, float d) {
  u32x2 v;
  v.x = (u32)f2b(a) | ((u32)f2b(b) << 16);
  v.y = (u32)f2b(c) | ((u32)f2b(d) << 16);
  *(u32x2*)p = v;
}

// pack 4 f32x4 -> two bf16x8
__device__ __forceinline__ void cvt16(const float4& a, const float4& b,
                                      const float4& c, const float4& d,
                                      bf16x8& lo, bf16x8& hi) {
  lo[0] = (short)f2b(a.x); lo[1] = (short)f2b(a.y); lo[2] = (short)f2b(a.z); lo[3] = (short)f2b(a.w);
  lo[4] = (short)f2b(b.x); lo[5] = (short)f2b(b.y); lo[6] = (short)f2b(b.z); lo[7] = (short)f2b(b.w);
  hi[0] = (short)f2b(c.x); hi[1] = (short)f2b(c.y); hi[2] = (short)f2b(c.z); hi[3] = (short)f2b(c.w);
  hi[4] = (short)f2b(d.x); hi[5] = (short)f2b(d.y); hi[6] = (short)f2b(d.z); hi[7] = (short)f2b(d.w);
}

// async global->LDS, 16B per lane; LDS dest = wave-uniform base + lane*16
__device__ __forceinline__ void async16(const void* g, void* l) {
  __builtin_amdgcn_global_load_lds(
      (const __attribute__((address_space(1))) unsigned int*)(uintptr_t)g,
      (__attribute__((address_space(3))) unsigned int*)(unsigned int)(uintptr_t)l,
      16, 0, 0);
}

// ---------------------------------------------------------------------------
// Kernel 1: fused RMSNorm(emb)+RMSNorm(hidden) -> x = concat([e,h]) as BF16
// ---------------------------------------------------------------------------
__global__ __launch_bounds__(256) void norm_concat_kernel(
    const float* __restrict__ emb, const float* __restrict__ hid,
    const float* __restrict__ w_e, const float* __restrict__ w_h,
    u16* __restrict__ x)
{
  const int row = blockIdx.x;
  const int t = threadIdx.x;
  const float* e = emb + (size_t)row * H_;
  const float* h = hid + (size_t)row * H_;

  const float4 ev0 = *(const float4*)&e[t * 4];
  const float4 ev1 = *(const float4*)&e[t * 4 + 1024];
  const float4 hv0 = *(const float4*)&h[t * 4];
  const float4 hv1 = *(const float4*)&h[t * 4 + 1024];

  float se = ev0.x*ev0.x + ev0.y*ev0.y + ev0.z*ev0.z + ev0.w*ev0.w
           + ev1.x*ev1.x + ev1.y*ev1.y + ev1.z*ev1.z + ev1.w*ev1.w;
  float sh = hv0.x*hv0.x + hv0.y*hv0.y + hv0.z*hv0.z + hv0.w*hv0.w
           + hv1.x*hv1.x + hv1.y*hv1.y + hv1.z*hv1.z + hv1.w*hv1.w;

  #pragma unroll
  for (int m = 1; m < 64; m <<= 1) {
    se += __shfl_xor(se, m);
    sh += __shfl_xor(sh, m);
  }
  __shared__ float red[8];
  const int wv = t >> 6;
  if ((t & 63) == 0) { red[wv] = se; red[4 + wv] = sh; }
  __syncthreads();
  se = red[0] + red[1] + red[2] + red[3];
  sh = red[4] + red[5] + red[6] + red[7];

  const float re = 1.0f / sqrtf(se * (1.0f / H_) + 1e-6f);
  const float rh = 1.0f / sqrtf(sh * (1.0f / H_) + 1e-6f);

  const float4 we0 = *(const float4*)&w_e[t * 4];
  const float4 we1 = *(const float4*)&w_e[t * 4 + 1024];
  const float4 wh0 = *(const float4*)&w_h[t * 4];
  const float4 wh1 = *(const float4*)&w_h[t * 4 + 1024];

  u16* xr = x + (size_t)row * (2 * H_);
  st_bf4(&xr[t * 4],        ev0.x*re*we0.x, ev0.y*re*we0.y, ev0.z*re*we0.z, ev0.w*re*we0.w);
  st_bf4(&xr[t * 4 + 1024], ev1.x*re*we1.x, ev1.y*re*we1.y, ev1.z*re*we1.z, ev1.w*re*we1.w);
  st_bf4(&xr[2048 + t * 4],        hv0.x*rh*wh0.x, hv0.y*rh*wh0.y, hv0.z*rh*wh0.z, hv0.w*rh*wh0.w);
  st_bf4(&xr[2048 + t * 4 + 1024], hv1.x*rh*wh1.x, hv1.y*rh*wh1.y, hv1.z*rh*wh1.z, hv1.w*rh*wh1.w);
}

// ---------------------------------------------------------------------------
// Kernel 2: RMSNorm f32 in -> BF16 out (post-attention norm)
// ---------------------------------------------------------------------------
__global__ __launch_bounds__(256) void rmsnorm_kernel(
    const float* __restrict__ in, const float* __restrict__ w, u16* __restrict__ outp)
{
  const int row = blockIdx.x;
  const int t = threadIdx.x;
  const float* p = in + (size_t)row * H_;
  const float4 v0 = *(const float4*)&p[t * 4];
  const float4 v1 = *(const float4*)&p[t * 4 + 1024];
  float s = v0.x*v0.x + v0.y*v0.y + v0.z*v0.z + v0.w*v0.w
          + v1.x*v1.x + v1.y*v1.y + v1.z*v1.z + v1.w*v1.w;
  #pragma unroll
  for (int m = 1; m < 64; m <<= 1) s += __shfl_xor(s, m);
  __shared__ float red[4];
  const int wv = t >> 6;
  if ((t & 63) == 0) red[wv] = s;
  __syncthreads();
  s = red[0] + red[1] + red[2] + red[3];
  const float rs = 1.0f / sqrtf(s * (1.0f / H_) + 1e-6f);

  const float4 w0 = *(const float4*)&w[t * 4];
  const float4 w1 = *(const float4*)&w[t * 4 + 1024];
  u16* orow = outp + (size_t)row * H_;
  st_bf4(&orow[t * 4],        v0.x*rs*w0.x, v0.y*rs*w0.y, v0.z*rs*w0.z, v0.w*rs*w0.w);
  st_bf4(&orow[t * 4 + 1024], v1.x*rs*w1.x, v1.y*rs*w1.y, v1.z*rs*w1.z, v1.w*rs*w1.w);
}

// ---------------------------------------------------------------------------
// Kernel 3: weight f32->bf16 converters
// convert6: wq|wk|wv|wo|wg|wu packed contiguously into dst (element order)
// ---------------------------------------------------------------------------
__global__ __launch_bounds__(256) void convert6_kernel(
    const float* __restrict__ wq, const float* __restrict__ wk, const float* __restrict__ wv,
    const float* __restrict__ wo, const float* __restrict__ wg, const float* __restrict__ wu,
    u16* __restrict__ dst)
{
  const size_t i8 = ((size_t)blockIdx.x * 256 + threadIdx.x) * 8;
  const float* s; size_t base;
  if      (i8 <  8388608) { s = wq; base = 0; }
  else if (i8 < 10485760) { s = wk; base = 8388608; }
  else if (i8 < 12582912) { s = wv; base = 10485760; }
  else if (i8 < 16777216) { s = wo; base = 12582912; }
  else if (i8 < 33554432) { s = wg; base = 16777216; }
  else                    { s = wu; base = 33554432; }
  const float4 a = *(const float4*)&s[i8 - base];
  const float4 b = *(const float4*)&s[i8 - base + 4];
  bf16x8 r;
  r[0] = (short)f2b(a.x); r[1] = (short)f2b(a.y); r[2] = (short)f2b(a.z); r[3] = (short)f2b(a.w);
  r[4] = (short)f2b(b.x); r[5] = (short)f2b(b.y); r[6] = (short)f2b(b.z); r[7] = (short)f2b(b.w);
  *(bf16x8*)&dst[i8] = r;
}

__global__ __launch_bounds__(256) void convert1_kernel(
    const float* __restrict__ src, u16* __restrict__ dst)
{
  const size_t i8 = ((size_t)blockIdx.x * 256 + threadIdx.x) * 8;
  const float4 a = *(const float4*)&src[i8];
  const float4 b = *(const float4*)&src[i8 + 4];
  bf16x8 r;
  r[0] = (short)f2b(a.x); r[1] = (short)f2b(a.y); r[2] = (short)f2b(a.z); r[3] = (short)f2b(a.w);
  r[4] = (short)f2b(b.x); r[5] = (short)f2b(b.y); r[6] = (short)f2b(b.z); r[7] = (short)f2b(b.w);
  *(bf16x8*)&dst[i8] = r;
}

// ---------------------------------------------------------------------------
// Kernel 4: BF16 MFMA NT-GEMM (m97 structure)  C[M,N] = A[M,K] * Bw[N,K]^T
// 128x128 tile, BK=32, 256 thr (4 waves, 2x2), wave = 4x4 of 16x16x32 MFMA.
// MODE 0: f32 C = acc   MODE 1: f32 C = acc + Xf32
// MODE 2: bf16 C = acc  MODE 3: bf16 C = silu(Xbf16) * acc
// ---------------------------------------------------------------------------
template <int MODE>
__global__ __launch_bounds__(256) void gemm_bf16_kernel(
    const u16* __restrict__ A, const u16* __restrict__ Bw,
    void* Cv, const void* Xv, int M, int N, int K)
{
  __shared__ __align__(16) u16 As[128 * 32];
  __shared__ __align__(16) u16 Bs[128 * 32];
  const int t = threadIdx.x;
  const int lane = t & 63;
  const int w = t >> 6;
  const int wr = w >> 1, wc = w & 1;
  const int row0 = blockIdx.y * 128;
  const int col0 = blockIdx.x * 128;

  f32x4 acc[4][4];
  #pragma unroll
  for (int i = 0; i < 4; ++i)
    #pragma unroll
    for (int j = 0; j < 4; ++j)
      #pragma unroll
      for (int r = 0; r < 4; ++r) acc[i][j][r] = 0.f;

  const int srow = lane >> 2;
  const int skc  = (lane & 3) * 8;
  const u16* Ag = A  + (size_t)(row0 + w * 32 + srow) * K + skc;
  const u16* Bg = Bw + (size_t)(col0 + w * 32 + srow) * K + skc;
  u16* AsW = &As[w * 32 * 32];
  u16* BsW = &Bs[w * 32 * 32];

  const int fr = lane & 15;
  const int fq = (lane >> 4) * 8;

  for (int k0 = 0; k0 < K; k0 += 32) {
    __syncthreads();
    async16(Ag + k0,                  AsW);
    async16(Ag + k0 + (size_t)16 * K, AsW + 16 * 32);
    async16(Bg + k0,                  BsW);
    async16(Bg + k0 + (size_t)16 * K, BsW + 16 * 32);
    __syncthreads();

    bf16x8 af[4], bfr[4];
    #pragma unroll
    for (int ti = 0; ti < 4; ++ti)
      af[ti] = *(const bf16x8*)&As[(wr * 64 + ti * 16 + fr) * 32 + fq];
    #pragma unroll
    for (int tj = 0; tj < 4; ++tj)
      bfr[tj] = *(const bf16x8*)&Bs[(wc * 64 + tj * 16 + fr) * 32 + fq];
    #pragma unroll
    for (int ti = 0; ti < 4; ++ti)
      #pragma unroll
      for (int tj = 0; tj < 4; ++tj)
        acc[ti][tj] = __builtin_amdgcn_mfma_f32_16x16x32_bf16(af[ti], bfr[tj], acc[ti][tj], 0, 0, 0);
  }

  float* Cf = (float*)Cv;
  u16*  Cb = (u16*)Cv;
  const float* Xf = (const float*)Xv;
  const u16*  Xb = (const u16*)Xv;
  const int rbase = (lane >> 4) * 4;
  const int cofs  = lane & 15;
  #pragma unroll
  for (int ti = 0; ti < 4; ++ti) {
    #pragma unroll
    for (int r = 0; r < 4; ++r) {
      const int gr = row0 + wr * 64 + ti * 16 + rbase + r;
      #pragma unroll
      for (int tj = 0; tj < 4; ++tj) {
        const int gc = col0 + wc * 64 + tj * 16 + cofs;
        const size_t off = (size_t)gr * N + gc;
        const float v = acc[ti][tj][r];
        if constexpr (MODE == 0) {
          Cf[off] = v;
        } else if constexpr (MODE == 1) {
          Cf[off] = v + Xf[off];
        } else if constexpr (MODE == 2) {
          Cb[off] = f2b(v);
        } else {
          const float g = b2f(Xb[off]);
          Cb[off] = f2b((g / (1.f + __expf(-g))) * v);
        }
      }
    }
  }
}

// ---------------------------------------------------------------------------
// Kernel 5: RoPE in-place on fused qkv f32 buffer [M][3072]
// q: cols h*64 (h<32); k: cols 2048 + kh*64 (kh<8). pair (i, i+32).
// ---------------------------------------------------------------------------
__global__ __launch_bounds__(256) void rope_kernel(
    float* __restrict__ qkv, const int* __restrict__ pid)
{
  const int idx = blockIdx.x * 256 + threadIdx.x;
  const int total = M_ * (NH_ + NKV_) * 32;   // 2,621,440
  if (idx >= total) return;
  const int row = idx / 1280;
  const int rem = idx - row * 1280;
  const int head = rem >> 5;
  const int i = rem & 31;
  const int col = (head < NH_) ? head * 64 : 2048 + (head - NH_) * 64;
  float* base = qkv + (size_t)row * 3072 + col;
  const int pos = pid[row] + LCK_;
  const float invf = powf(10000.0f, -(float)i * (1.0f / 32.0f));
  const float ang = (float)pos * invf;
  const float c  = cosf(ang);
  const float sn = sinf(ang);
  const float x0 = base[i];
  const float x1 = base[i + 32];
  base[i]      = x0 * c - x1 * sn;
  base[i + 32] = x1 * c + x0 * sn;
}

// ---------------------------------------------------------------------------
// Kernel 6: MFMA flash attention. Block = (b,h,qt): 64 q rows, 4 waves x 16.
// QK^T and PV via mfma_f32_16x16x32_bf16; K/V staged bf16 in LDS (V transposed),
// P round-trips LDS in A-layout. Rows padded to 72 u16 (144B: 16B-aligned,
// bank-rotated). Online softmax per wave. 3 diagonal extras merged at end.
// ---------------------------------------------------------------------------
__global__ __launch_bounds__(256) void attn_kernel(
    const float* __restrict__ qkv,
    const float* __restrict__ ck, const float* __restrict__ cv,
    u16* __restrict__ ao)
{
  const int bid = blockIdx.x;
  const int qt = bid & 15;
  const int bh = bid >> 4;
  const int h = bh & 31;
  const int b = bh >> 5;
  const int t = threadIdx.x;
  const int lane = t & 63;
  const int w = t >> 6;
  const int qbase = qt * 64;

  const int fr = lane & 15;            // A-frag m / B-frag n
  const int fq = (lane >> 4) * 8;      // frag k base
  const int rbase = (lane >> 4) * 4;   // C-layout row base
  const int cofs = lane & 15;          // C-layout col

  __shared__ __align__(16) u16 Qs[64 * 72];    // [qrow][d], pre-scaled bf16
  __shared__ __align__(16) u16 Ks[64 * 72];    // [key][d]
  __shared__ __align__(16) u16 Vts[64 * 72];   // [d][key]
  __shared__ __align__(16) u16 Ps[64 * 72];    // [qrow][key] per-wave slices
  __shared__ float Ls[192];

  const size_t bh_off = (size_t)b * NH_ + h;
  const float* K0 = ck + bh_off * S_ * D_;
  const float* V0 = cv + bh_off * S_ * D_;

  // stage Q once: thread t -> row sr = t>>2, d-chunk sc = (t&3)*16
  const int sr = t >> 2;
  const int sc = (t & 3) * 16;
  {
    const float* qg = qkv + (size_t)(b * S_ + qbase + sr) * 3072 + h * 64 + sc;
    float4 a = *(const float4*)&qg[0], bb = *(const float4*)&qg[4],
           c = *(const float4*)&qg[8], d = *(const float4*)&qg[12];
    a.x*=0.125f; a.y*=0.125f; a.z*=0.125f; a.w*=0.125f;
    bb.x*=0.125f; bb.y*=0.125f; bb.z*=0.125f; bb.w*=0.125f;
    c.x*=0.125f; c.y*=0.125f; c.z*=0.125f; c.w*=0.125f;
    d.x*=0.125f; d.y*=0.125f; d.z*=0.125f; d.w*=0.125f;
    bf16x8 lo, hi; cvt16(a, bb, c, d, lo, hi);
    *(bf16x8*)&Qs[sr * 72 + sc] = lo;
    *(bf16x8*)&Qs[sr * 72 + sc + 8] = hi;
  }

  float m_r[4], l_r[4];
  f32x4 Oacc[4];
  #pragma unroll
  for (int r = 0; r < 4; ++r) { m_r[r] = -3.0e38f; l_r[r] = 0.f; }
  #pragma unroll
  for (int dt = 0; dt < 4; ++dt)
    #pragma unroll
    for (int r = 0; r < 4; ++r) Oacc[dt][r] = 0.f;

  for (int kt = 0; kt <= qt; ++kt) {
    __syncthreads();   // prior QK/PV reads of Ks/Vts done
    {
      const float* kg = K0 + (size_t)(kt * 64 + sr) * D_ + sc;
      float4 a = *(const float4*)&kg[0], bb = *(const float4*)&kg[4],
             c = *(const float4*)&kg[8], d = *(const float4*)&kg[12];
      bf16x8 lo, hi; cvt16(a, bb, c, d, lo, hi);
      *(bf16x8*)&Ks[sr * 72 + sc] = lo;
      *(bf16x8*)&Ks[sr * 72 + sc + 8] = hi;
      const float* vg = V0 + (size_t)(kt * 64 + sr) * D_ + sc;
      float4 va = *(const float4*)&vg[0], vb4 = *(const float4*)&vg[4],
             vc = *(const float4*)&vg[8], vd = *(const float4*)&vg[12];
      const float vv[16] = {va.x,va.y,va.z,va.w, vb4.x,vb4.y,vb4.z,vb4.w,
                            vc.x,vc.y,vc.z,vc.w, vd.x,vd.y,vd.z,vd.w};
      #pragma unroll
      for (int i = 0; i < 16; ++i) Vts[(sc + i) * 72 + sr] = f2b(vv[i]);
    }
    __syncthreads();   // staged tiles visible

    // ---- QK^T: wave w computes S[16 rows][64 keys] ----
    const bf16x8 qa0 = *(const bf16x8*)&Qs[(w * 16 + fr) * 72 + fq];
    const bf16x8 qa1 = *(const bf16x8*)&Qs[(w * 16 + fr) * 72 + 32 + fq];
    f32x4 sacc[4];
    #pragma unroll
    for (int nt = 0; nt < 4; ++nt) {
      const bf16x8 kb0 = *(const bf16x8*)&Ks[(nt * 16 + fr) * 72 + fq];
      const bf16x8 kb1 = *(const bf16x8*)&Ks[(nt * 16 + fr) * 72 + 32 + fq];
      f32x4 z; z[0]=0.f; z[1]=0.f; z[2]=0.f; z[3]=0.f;
      z = __builtin_amdgcn_mfma_f32_16x16x32_bf16(qa0, kb0, z, 0, 0, 0);
      sacc[nt] = __builtin_amdgcn_mfma_f32_16x16x32_bf16(qa1, kb1, z, 0, 0, 0);
    }
    if (kt == qt) {   // causal mask inside diagonal tile
      #pragma unroll
      for (int nt = 0; nt < 4; ++nt) {
        const int key = nt * 16 + cofs;
        #pragma unroll
        for (int r = 0; r < 4; ++r)
          if (key > w * 16 + rbase + r) sacc[nt][r] = -3.0e38f;
      }
    }

    // ---- online softmax (per wave, rows rbase..rbase+3 of wave's 16) ----
    #pragma unroll
    for (int r = 0; r < 4; ++r) {
      float rm = fmaxf(fmaxf(sacc[0][r], sacc[1][r]), fmaxf(sacc[2][r], sacc[3][r]));
      rm = fmaxf(rm, __shfl_xor(rm, 1));
      rm = fmaxf(rm, __shfl_xor(rm, 2));
      rm = fmaxf(rm, __shfl_xor(rm, 4));
      rm = fmaxf(rm, __shfl_xor(rm, 8));
      const float mnew = fmaxf(m_r[r], rm);
      const float alpha = __expf(m_r[r] - mnew);
      float p0 = __expf(sacc[0][r] - mnew);
      float p1 = __expf(sacc[1][r] - mnew);
      float p2 = __expf(sacc[2][r] - mnew);
      float p3 = __expf(sacc[3][r] - mnew);
      float rs = p0 + p1 + p2 + p3;
      rs += __shfl_xor(rs, 1);
      rs += __shfl_xor(rs, 2);
      rs += __shfl_xor(rs, 4);
      rs += __shfl_xor(rs, 8);
      l_r[r] = l_r[r] * alpha + rs;
      m_r[r] = mnew;
      #pragma unroll
      for (int dt = 0; dt < 4; ++dt) Oacc[dt][r] *= alpha;
      u16* prow = &Ps[(w * 16 + rbase + r) * 72 + cofs];
      prow[0]  = f2b(p0);
      prow[16] = f2b(p1);
      prow[32] = f2b(p2);
      prow[48] = f2b(p3);
    }

    // ---- PV: O[16 rows][64 d] += P @ V (wave-local P, block Vts) ----
    const bf16x8 pa0 = *(const bf16x8*)&Ps[(w * 16 + fr) * 72 + fq];
    const bf16x8 pa1 = *(const bf16x8*)&Ps[(w * 16 + fr) * 72 + 32 + fq];
    #pragma unroll
    for (int dt = 0; dt < 4; ++dt) {
      const bf16x8 vb0 = *(const bf16x8*)&Vts[(dt * 16 + fr) * 72 + fq];
      const bf16x8 vb1 = *(const bf16x8*)&Vts[(dt * 16 + fr) * 72 + 32 + fq];
      Oacc[dt] = __builtin_amdgcn_mfma_f32_16x16x32_bf16(pa0, vb0, Oacc[dt], 0, 0, 0);
      Oacc[dt] = __builtin_amdgcn_mfma_f32_16x16x32_bf16(pa1, vb1, Oacc[dt], 0, 0, 0);
    }
  }

  // ---- 3 diagonal extras: logits ----
  if (t < 192) {
    const int n = t >> 6;
    const int r = t & 63;
    const int qp = qbase + r;
    const float* kp;
    if (n < 2) kp = ck + ((((size_t)(n + 1) * B_ + b) * NH_ + h) * S_ + qp) * D_;
    else       kp = qkv + (size_t)(b * S_ + qp) * 3072 + 2048 + (h >> 2) * 64;
    float e = 0.f;
    #pragma unroll 16
    for (int d = 0; d < 64; ++d) e = fmaf(b2f(Qs[r * 72 + d]), kp[d], e);
    Ls[n * 64 + r] = e;
  }
  __syncthreads();

  // ---- merge extras + normalize + store bf16 ----
  #pragma unroll
  for (int r = 0; r < 4; ++r) {
    const int qr = w * 16 + rbase + r;
    const int qp = qbase + qr;
    const float e0 = Ls[qr], e1 = Ls[64 + qr], e2 = Ls[128 + qr];
    const float mnew = fmaxf(fmaxf(m_r[r], e0), fmaxf(e1, e2));
    const float alpha = __expf(m_r[r] - mnew);
    const float p0 = __expf(e0 - mnew);
    const float p1 = __expf(e1 - mnew);
    const float p2 = __expf(e2 - mnew);
    const float inv = 1.0f / (l_r[r] * alpha + p0 + p1 + p2);
    const float* v1p = cv + ((((size_t)1 * B_ + b) * NH_ + h) * S_ + qp) * D_;
    const float* v2p = cv + ((((size_t)2 * B_ + b) * NH_ + h) * S_ + qp) * D_;
    const float* v3p = qkv + (size_t)(b * S_ + qp) * 3072 + 2560 + (h >> 2) * 64;
    u16* aorow = ao + (size_t)(b * S_ + qp) * 2048 + h * 64;
    #pragma unroll
    for (int dt = 0; dt < 4; ++dt) {
      const int col = dt * 16 + cofs;
      const float o = (Oacc[dt][r] * alpha + p0 * v1p[col] + p1 * v2p[col] + p2 * v3p[col]) * inv;
      aorow[col] = f2b(o);
    }
  }
}

// ---------------------------------------------------------------------------
extern "C" void kernel_launch(void* const* d_in, const int* in_sizes, int n_in,
                              void* d_out, int out_size, void* d_ws, size_t ws_size,
                              hipStream_t stream)
{
  const float* input_emb = (const float*)d_in[0];
  const float* hidden    = (const float*)d_in[1];
  const float* cache_k   = (const float*)d_in[2];
  const float* cache_v   = (const float*)d_in[3];
  const int*   pos_ids   = (const int*)d_in[5];
  const float* wq = (const float*)d_in[6];
  const float* wk = (const float*)d_in[7];
  const float* wv = (const float*)d_in[8];
  const float* wo = (const float*)d_in[9];
  const float* wg = (const float*)d_in[10];
  const float* wu = (const float*)d_in[11];
  const float* wd = (const float*)d_in[12];
  const float* w_hidden_norm = (const float*)d_in[13];
  const float* w_input_ln    = (const float*)d_in[14];
  const float* w_post_ln     = (const float*)d_in[15];
  float* out = (float*)d_out;

  // Workspace (bytes), peak 160 MiB, lifetime-aliased:
  //  [0,25.2M)      wqkv_b (wq|wk|wv packed rows = 3072x4096)  -> dead after qkv GEMM
  //  [25.2,33.6M)   wo_b   -> dead after wo GEMM
  //  [33.6,67.1M)   wg_b   -> dead after gate GEMM; then wd_b
  //  [67.1,100.7M)  wu_b   -> dead after up GEMM
  //  [100.7,117.4M) x_b    -> dead after qkv GEMM; then hn
  //  [117.4,142.6M) qkvf f32 [M][3072] -> dead after attn; then gbb (33.5M, +ao region)
  //  [142.6,151M)   ao bf16 -> dead after wo GEMM
  //  [151,167.8M)   h2 f32 -> live to end
  char* wsb = (char*)d_ws;
  u16*   wall   = (u16*)(wsb + 0);
  u16*   wqkv_b = wall;
  u16*   wo_b   = (u16*)(wsb + 25165824);
  u16*   wg_b   = (u16*)(wsb + 33554432);
  u16*   wu_b   = (u16*)(wsb + 67108864);
  u16*   xb     = (u16*)(wsb + 100663296);
  float* qkvf   = (float*)(wsb + 117440512);
  u16*   ao     = (u16*)(wsb + 142606336);
  float* h2     = (float*)(wsb + 150994944);
  u16*   hn     = (u16*)(wsb + 100663296);   // alias x_b
  u16*   gbb    = (u16*)(wsb + 117440512);   // alias qkvf+ao
  u16*   gub    = (u16*)(wsb + 0);           // alias wqkv_b+wo_b
  u16*   wd_b   = (u16*)(wsb + 33554432);    // alias wg_b

  // 1. weights -> bf16
  convert6_kernel<<<24576, 256, 0, stream>>>(wq, wk, wv, wo, wg, wu, wall);
  // 2. fused norms + concat -> bf16 x
  norm_concat_kernel<<<M_, 256, 0, stream>>>(input_emb, hidden, w_input_ln, w_hidden_norm, xb);
  // 3. fused QKV projection (N=3072) -> f32 qkvf
  gemm_bf16_kernel<0><<<dim3(24, 16), 256, 0, stream>>>(xb, wqkv_b, qkvf, nullptr, M_, 3072, 4096);
  // 4. RoPE in-place on qkvf
  rope_kernel<<<10240, 256, 0, stream>>>(qkvf, pos_ids);
  // 5. MFMA flash attention -> bf16 ao
  attn_kernel<<<B_ * NH_ * (S_ / 64), 256, 0, stream>>>(qkvf, cache_k, cache_v, ao);
  // 6. output projection + residual(hidden) -> f32 h2
  gemm_bf16_kernel<1><<<dim3(16, 16), 256, 0, stream>>>(ao, wo_b, h2, hidden, M_, 2048, 2048);
  // 7. post-attention RMSNorm -> bf16 hn
  rmsnorm_kernel<<<M_, 256, 0, stream>>>(h2, w_post_ln, hn);
  // 8. gate GEMM -> bf16 gbb
  gemm_bf16_kernel<2><<<dim3(64, 16), 256, 0, stream>>>(hn, wg_b, gbb, nullptr, M_, 8192, 2048);
  // 9. wd -> bf16 (wg_b region now dead)
  convert1_kernel<<<8192, 256, 0, stream>>>(wd, wd_b);
  // 10. up GEMM, epilogue silu(gate)*up -> bf16 gub
  gemm_bf16_kernel<3><<<dim3(64, 16), 256, 0, stream>>>(hn, wu_b, gub, gbb, M_, 8192, 2048);
  // 11. down GEMM + residual(h2) -> out f32
  gemm_bf16_kernel<1><<<dim3(16, 16), 256, 0, stream>>>(gub, wd_b, out, h2, M_, 2048, 8192);
}